// Round 10
// baseline (293.797 us; speedup 1.0000x reference)
//
#include <hip/hip_runtime.h>
#include <math.h>

#define N_NODES 20000
#define E_EDGES 320000
#define F_DIM   960
#define S_DIM   256
#define QTAB    2048
#define ASTRIDE 264   // LDS A row stride in bf16 elems
#define CAP     64    // max deg per node (Poisson(16): P(deg>=64) ~ 2e-18)

typedef __attribute__((ext_vector_type(8))) short short8;
typedef __attribute__((ext_vector_type(4))) float f32x4;
typedef _Float16 half8 __attribute__((ext_vector_type(8)));

__device__ __forceinline__ float siluf(float x) {
    return x / (1.0f + __expf(-x));
}

__device__ __forceinline__ unsigned short bf16rn(float x) {
    unsigned u = __float_as_uint(x);
    return (unsigned short)((u + 0x7FFFu + ((u >> 16) & 1u)) >> 16);
}

// ---------------------------------------------------------------------------
// A: fold weights DIRECTLY into bf16 Bpack + We + c0 + zero cnt.
// Blocks: [0,128) fold->Bpack, [128,160) We, [160] c0, [161,240) cnt=0.
// ---------------------------------------------------------------------------
__global__ __launch_bounds__(256) void prep_kernel(
    const float* __restrict__ W_sc, const float* __restrict__ W_ed,
    const float* __restrict__ W_b1, const float* __restrict__ b_sc,
    const float* __restrict__ b_ed, const float* __restrict__ b_b1,
    const float* __restrict__ W_ai1, const float* __restrict__ W_ci1,
    unsigned short* __restrict__ Bpack, float* __restrict__ We, float* __restrict__ c0,
    int* __restrict__ cnt)
{
    const int b = blockIdx.x;
    const int tid = threadIdx.x;
    if (b < 128) {
        const int oct = b >> 2;                  // 0..31, uniform per block
        const int j   = (b & 3) * 256 + tid;     // 0..1023
        const int k0  = oct * 8;
        float s[8];
        #pragma unroll
        for (int jj = 0; jj < 8; ++jj) s[jj] = 0.0f;
        if (j < 256) {
            for (int m = 0; m < 256; ++m) {
                float wv = W_b1[m * 256 + j];
                #pragma unroll
                for (int jj = 0; jj < 8; ++jj) s[jj] += W_sc[(k0 + jj) * 256 + m] * wv;
            }
        } else if (j < 512) {
            const int j2 = j - 256;
            for (int m = 0; m < 256; ++m) {
                float wv = W_b1[(256 + m) * 256 + j2];
                #pragma unroll
                for (int jj = 0; jj < 8; ++jj) s[jj] += W_sc[(k0 + jj) * 256 + m] * wv;
            }
        } else if (j < 768) {
            #pragma unroll
            for (int jj = 0; jj < 8; ++jj) s[jj] = W_ai1[(k0 + jj) * 256 + (j - 512)];
        } else {
            #pragma unroll
            for (int jj = 0; jj < 8; ++jj) s[jj] = W_ci1[(k0 + jj) * 256 + (j - 768)];
        }
        unsigned short o[8];
        #pragma unroll
        for (int jj = 0; jj < 8; ++jj) o[jj] = bf16rn(s[jj]);
        unsigned short* dst = &Bpack[((oct >> 2) * 4096 + j * 4 + (oct & 3)) * 8];
        ushort4 lo; lo.x = o[0]; lo.y = o[1]; lo.z = o[2]; lo.w = o[3];
        ushort4 hi; hi.x = o[4]; hi.y = o[5]; hi.z = o[6]; hi.w = o[7];
        *(ushort4*)dst = lo;
        *(ushort4*)(dst + 4) = hi;
    } else if (b < 160) {
        const int t = (b - 128) * 256 + tid;     // 0..8191
        const int p = t >> 8, j = t & 255;
        float s = 0.0f;
        for (int m = 0; m < 256; ++m) s += W_ed[p * 256 + m] * W_b1[(512 + m) * 256 + j];
        We[t] = s;
    } else if (b == 160) {
        const int j = tid;
        float s = b_b1[j];
        for (int m = 0; m < 256; ++m) {
            s += b_sc[m] * (W_b1[m * 256 + j] + W_b1[(256 + m) * 256 + j]);
            s += b_ed[m] * W_b1[(512 + m) * 256 + j];
        }
        c0[j] = s;
    } else {
        const int idx = (b - 161) * 256 + tid;
        if (idx < N_NODES) cnt[idx] = 0;
    }
}

// ---------------------------------------------------------------------------
// B: fused rank-histogram + Tab(f16) + scal->bf16 pack (R8 structure).
// Blocks: [0,1250) rank, [1250,3298) table, [3298,8298) scalp.
// ---------------------------------------------------------------------------
__global__ void aux_kernel(const int* __restrict__ ei, int* __restrict__ cnt, int* __restrict__ rank,
                           const float* __restrict__ We, _Float16* __restrict__ Tab,
                           const float* __restrict__ nf, unsigned short* __restrict__ scalp)
{
    int b = blockIdx.x;
    if (b < 1250) {
        int i = b * 256 + threadIdx.x;          // 320000 exact
        rank[i] = atomicAdd(&cnt[ei[E_EDGES + i]], 1);
    } else if (b < 3298) {
        int idx = (b - 1250) * 256 + threadIdx.x;  // 524288 exact
        int q = idx >> 8, j = idx & 255;
        float nrm = 5.0f * (float)q / (float)(QTAB - 1);
        const float start = 0.006737946999085467f;  // exp(-5)
        const float mustep = (1.0f - start) / 31.0f;
        const float bx = (2.0f / 32.0f) * (1.0f - start);
        const float beta = 1.0f / (bx * bx);
        const float PI_F = 3.14159265358979323846f;
        float cc = (nrm < 5.0f) ? 0.5f * (__cosf(PI_F * nrm * 0.2f) + 1.0f) : 0.0f;
        float t = __expf(-nrm);
        float s = 0.0f;
        for (int k = 0; k < 32; ++k) {
            float dm = t - (start + (float)k * mustep);
            s += __expf(-beta * dm * dm) * We[k * 256 + j];
        }
        Tab[idx] = (_Float16)(cc * s);
    } else {
        int idx = (b - 3298) * 256 + threadIdx.x;  // 1.28M exact (x4 elems)
        int base = idx * 4;
        int n = base >> 8, k = base & 255;
        float4 a4 = *(const float4*)&nf[(size_t)n * F_DIM + k];
        ushort4 b4;
        b4.x = bf16rn(a4.x); b4.y = bf16rn(a4.y);
        b4.z = bf16rn(a4.z); b4.w = bf16rn(a4.w);
        *(ushort4*)&scalp[n * 256 + k] = b4;
    }
}

// ---------------------------------------------------------------------------
// C+E: node GEMM (R8 structure: BM=32, ONE col-group/block, bf16 scalp
// staging, blocks 1..2500) + exclusive scan of cnt at blockIdx 0 (dispatched
// FIRST -> overlaps GEMM; R7 proved tail placement exposes the scan).
// A/B vs R9: only staging dtype differs (scalp bf16 vs nf fp32).
// ---------------------------------------------------------------------------
__global__ __launch_bounds__(256) void mfma_scan_kernel(
    const unsigned short* __restrict__ scalp, const unsigned short* __restrict__ Bpack,
    const float* __restrict__ c0,
    const float* __restrict__ b_ai1, const float* __restrict__ W_ai2, const float* __restrict__ b_ai2,
    const float* __restrict__ b_ci1, const float* __restrict__ W_ci2, const float* __restrict__ b_ci2,
    _Float16* __restrict__ u, _Float16* __restrict__ v,
    float* __restrict__ bsumseed, float* __restrict__ out_ai,
    const int* __restrict__ cnt, int* __restrict__ startA)
{
    __shared__ unsigned short A[32 * ASTRIDE];   // 16.9 KB
    __shared__ float red[32 * 4];

    const int tid = threadIdx.x;

    if (blockIdx.x == 0) {
        // ---- exclusive scan, 256 threads x 79 nodes, 2-pass
        int* ps = (int*)A;
        const int base = tid * 79;
        int ssum = 0;
        for (int i = 0; i < 79; ++i) {
            int idx = base + i;
            ssum += (idx < N_NODES) ? cnt[idx] : 0;
        }
        ps[tid] = ssum;
        __syncthreads();
        for (int off = 1; off < 256; off <<= 1) {
            int vv = (tid >= off) ? ps[tid - off] : 0;
            __syncthreads();
            ps[tid] += vv;
            __syncthreads();
        }
        int run = ps[tid] - ssum;   // exclusive
        for (int i = 0; i < 79; ++i) {
            int idx = base + i;
            if (idx < N_NODES) { int c = cnt[idx]; startA[idx] = run; run += c; }
        }
        return;
    }

    const int bid = blockIdx.x - 1;              // 0..2499
    const int w = tid >> 6, lane = tid & 63;
    const int cg = bid & 3;                      // col-group 0..3
    const int m0 = (bid >> 2) * 32;              // 625*32 = 20000 exact
    const int col16 = lane & 15, quad = lane >> 4;

    #pragma unroll
    for (int it = 0; it < 4; ++it) {
        int idx = (it * 256 + tid) * 8;          // bf16 elem 0..8191
        int r = idx >> 8, c = idx & 255;
        *(uint4*)&A[r * ASTRIDE + c] = *(const uint4*)&scalp[(size_t)(m0 + r) * 256 + c];
    }
    __syncthreads();

    f32x4 acc[2][4];
    #pragma unroll
    for (int mt = 0; mt < 2; ++mt)
        #pragma unroll
        for (int nt = 0; nt < 4; ++nt)
            acc[mt][nt] = (f32x4){0.0f, 0.0f, 0.0f, 0.0f};

    const int colbase = cg * 256 + w * 64;

    for (int t = 0; t < 8; ++t) {
        short8 af[2];
        #pragma unroll
        for (int mt = 0; mt < 2; ++mt)
            af[mt] = *(const short8*)&A[(mt * 16 + col16) * ASTRIDE + t * 32 + quad * 8];
        short8 bf[4];
        #pragma unroll
        for (int nt = 0; nt < 4; ++nt)
            bf[nt] = *(const short8*)&Bpack[(((t * 1024 + colbase + nt * 16 + col16) * 4) + quad) * 8];
        #pragma unroll
        for (int mt = 0; mt < 2; ++mt)
            #pragma unroll
            for (int nt = 0; nt < 4; ++nt)
                acc[mt][nt] = __builtin_amdgcn_mfma_f32_16x16x32_bf16(af[mt], bf[nt], acc[mt][nt], 0, 0, 0);
    }

    if (cg == 0) {
        #pragma unroll
        for (int nt = 0; nt < 4; ++nt) {
            int jl = w * 64 + nt * 16 + col16;
            float c0v = c0[jl];
            #pragma unroll
            for (int mt = 0; mt < 2; ++mt)
                #pragma unroll
                for (int reg = 0; reg < 4; ++reg)
                    u[(size_t)(m0 + mt * 16 + quad * 4 + reg) * 256 + jl] = (_Float16)(acc[mt][nt][reg] + c0v);
        }
    } else if (cg == 1) {
        #pragma unroll
        for (int nt = 0; nt < 4; ++nt) {
            int jl = w * 64 + nt * 16 + col16;
            #pragma unroll
            for (int mt = 0; mt < 2; ++mt)
                #pragma unroll
                for (int reg = 0; reg < 4; ++reg)
                    v[(size_t)(m0 + mt * 16 + quad * 4 + reg) * 256 + jl] = (_Float16)(acc[mt][nt][reg]);
        }
    } else {
        const float* b1 = (cg == 2) ? b_ai1 : b_ci1;
        const float* w2 = (cg == 2) ? W_ai2 : W_ci2;
        float s[2][4] = {{0, 0, 0, 0}, {0, 0, 0, 0}};
        #pragma unroll
        for (int nt = 0; nt < 4; ++nt) {
            int jl = w * 64 + nt * 16 + col16;
            float bb = b1[jl], ww = w2[jl];
            #pragma unroll
            for (int mt = 0; mt < 2; ++mt)
                #pragma unroll
                for (int reg = 0; reg < 4; ++reg)
                    s[mt][reg] += siluf(acc[mt][nt][reg] + bb) * ww;
        }
        #pragma unroll
        for (int off = 1; off < 16; off <<= 1) {
            #pragma unroll
            for (int mt = 0; mt < 2; ++mt)
                #pragma unroll
                for (int reg = 0; reg < 4; ++reg)
                    s[mt][reg] += __shfl_xor(s[mt][reg], off);
        }
        if (col16 == 0) {
            #pragma unroll
            for (int mt = 0; mt < 2; ++mt)
                #pragma unroll
                for (int reg = 0; reg < 4; ++reg)
                    red[(mt * 16 + quad * 4 + reg) * 4 + w] = s[mt][reg];
        }
        __syncthreads();
        if (tid < 32) {
            float sum = red[tid * 4] + red[tid * 4 + 1] + red[tid * 4 + 2] + red[tid * 4 + 3];
            if (cg == 2) out_ai[m0 + tid] = expf(sum + b_ai2[0]);
            else         bsumseed[m0 + tid] = expf(sum + b_ci2[0]) + 1e-7f;  // ci + eps
        }
    }
}

// ---------------------------------------------------------------------------
// D: per-edge geometry + CSR scatter. geom[slot] = {rx, ry, rz, x}.
// ---------------------------------------------------------------------------
__global__ void edge_geom_kernel(const int* __restrict__ ei, const int* __restrict__ start,
                                 const int* __restrict__ rank, const float* __restrict__ pos,
                                 int2* __restrict__ sd, float4* __restrict__ geom)
{
    int i = blockIdx.x * 256 + threadIdx.x;
    if (i >= E_EDGES) return;
    int s = ei[i];
    int d = ei[E_EDGES + i];
    int slot = start[d] + rank[i];
    int2 p; p.x = s; p.y = d;
    sd[slot] = p;

    // rel = pos[dst] - pos[src]  (matches reference)
    float px = pos[3 * d + 0] - pos[3 * s + 0];
    float py = pos[3 * d + 1] - pos[3 * s + 1];
    float pz = pos[3 * d + 2] - pos[3 * s + 2];
    float nrm = sqrtf(px * px + py * py + pz * pz);
    float inv = 1.0f / (nrm + 1e-8f);
    float4 o;
    o.x = px * inv; o.y = py * inv; o.z = pz * inv;
    o.w = nrm * (float)(QTAB - 1) * 0.2f;
    geom[slot] = o;
}

// ---------------------------------------------------------------------------
// F1: edge-parallel MLP in CSR SLOT order, packed-f16 h-assembly.
// ---------------------------------------------------------------------------
__global__ __launch_bounds__(256) void edge_bij_kernel(
    const int2* __restrict__ sd, const float4* __restrict__ geom,
    const _Float16* __restrict__ u, const _Float16* __restrict__ v,
    const _Float16* __restrict__ Tab,
    const float* __restrict__ W_b2, const float* __restrict__ b_b2,
    float* __restrict__ bijV)
{
    const int l = threadIdx.x & 15;
    const int slot = blockIdx.x * 16 + (threadIdx.x >> 4);   // 20000*16 = 320000 exact
    const int2 e = sd[slot];
    const int src = e.x;
    const int dst = e.y;
    const float x = ((const float*)&geom[slot])[3];   // broadcast 4B load

    int qi = (int)x;
    float f = x - (float)qi;
    if (qi >= QTAB - 1) { qi = QTAB - 2; f = 1.0f; }
    const _Float16 fh = (_Float16)f;

    float w2c[16];
    #pragma unroll
    for (int c = 0; c < 16; c += 4)
        *(float4*)&w2c[c] = *(const float4*)&W_b2[l * 16 + c];

    // 32-bit byte offsets (rows are 512 B).
    const unsigned lo = (unsigned)l * 32u;
    const char* ub = (const char*)u + ((unsigned)src * 512u + lo);
    const char* vb = (const char*)v + ((unsigned)dst * 512u + lo);
    const char* tb = (const char*)Tab + ((unsigned)qi * 512u + lo);

    half8 u0 = *(const half8*)(ub);
    half8 u1 = *(const half8*)(ub + 16);
    half8 v0 = *(const half8*)(vb);
    half8 v1 = *(const half8*)(vb + 16);
    half8 t00 = *(const half8*)(tb);
    half8 t01 = *(const half8*)(tb + 16);
    half8 t10 = *(const half8*)(tb + 512);
    half8 t11 = *(const half8*)(tb + 528);

    half8 h0 = (u0 + v0) + (t00 + fh * (t10 - t00));
    half8 h1 = (u1 + v1) + (t01 + fh * (t11 - t01));

    float acc = 0.0f;
    #pragma unroll
    for (int c = 0; c < 8; ++c) {
        float hf = (float)h0[c];
        float sig = __builtin_amdgcn_rcpf(1.0f + __expf(-hf));
        acc += w2c[c] * hf * sig;
    }
    #pragma unroll
    for (int c = 0; c < 8; ++c) {
        float hf = (float)h1[c];
        float sig = __builtin_amdgcn_rcpf(1.0f + __expf(-hf));
        acc += w2c[8 + c] * hf * sig;
    }
    #pragma unroll
    for (int off = 1; off < 16; off <<= 1) acc += __shfl_xor(acc, off);

    if (l == 0) bijV[slot] = acc + b_b2[0];
}

// ---------------------------------------------------------------------------
// F2: node-parallel softmax + outer-product. 16 lanes/node, CSR segment kept
// entirely in registers (CAP=64 -> 4 slots/lane, statically indexed).
// ---------------------------------------------------------------------------
__global__ __launch_bounds__(256) void node_reduce_kernel(
    const int* __restrict__ start, const int* __restrict__ cnt,
    const float* __restrict__ bijV, const float4* __restrict__ geom,
    const float* __restrict__ bsumseed, const float* __restrict__ out_ai,
    float* __restrict__ out_sigma, float* __restrict__ out_sg)
{
    const int grp = threadIdx.x >> 4;
    const int l = threadIdx.x & 15;
    const int g = blockIdx.x * 16 + grp;   // 1250*16 = 20000 exact
    const int st = start[g];
    const int deg = min(cnt[g], CAP);

    float bj[4], ex[4], ey[4], ez[4];
    bool ok[4];
    float m = -1e30f;
    #pragma unroll
    for (int k = 0; k < 4; ++k) {
        int i = l + k * 16;
        ok[k] = (i < deg);
        if (ok[k]) {
            float4 o = geom[st + i];
            bj[k] = bijV[st + i];
            ex[k] = o.x; ey[k] = o.y; ez[k] = o.z;
        } else {
            bj[k] = -1e30f; ex[k] = 0.0f; ey[k] = 0.0f; ez[k] = 0.0f;
        }
        m = fmaxf(m, bj[k]);
    }
    #pragma unroll
    for (int off = 1; off < 16; off <<= 1) m = fmaxf(m, __shfl_xor(m, off));

    float g4[4];
    float ssum = 0.0f;
    #pragma unroll
    for (int k = 0; k < 4; ++k) {
        g4[k] = ok[k] ? __expf(bj[k] - m) : 0.0f;
        ssum += g4[k];
    }
    #pragma unroll
    for (int off = 1; off < 16; off <<= 1) ssum += __shfl_xor(ssum, off);

    float invt = 1.0f / (ssum + bsumseed[g]);   // seed = ci + 1e-7

    float a0 = 0, a1 = 0, a2 = 0, a3 = 0, a4 = 0, a5 = 0, a6 = 0;
    #pragma unroll
    for (int k = 0; k < 4; ++k) {
        float gm = g4[k] * invt;
        a0 += gm * ex[k] * ex[k]; a1 += gm * ey[k] * ey[k]; a2 += gm * ez[k] * ez[k];
        a3 += gm * ex[k] * ey[k]; a4 += gm * ex[k] * ez[k]; a5 += gm * ey[k] * ez[k];
        a6 += gm;
    }
    #pragma unroll
    for (int off = 1; off < 16; off <<= 1) {
        a0 += __shfl_xor(a0, off); a1 += __shfl_xor(a1, off);
        a2 += __shfl_xor(a2, off); a3 += __shfl_xor(a3, off);
        a4 += __shfl_xor(a4, off); a5 += __shfl_xor(a5, off);
        a6 += __shfl_xor(a6, off);
    }

    if (l == 0) {
        float ai = out_ai[g];
        float* sg = &out_sigma[g * 9];
        float d0 = ai + 1e-6f;
        sg[0] = d0 - ai * a0;
        sg[1] = -ai * a3;
        sg[2] = -ai * a4;
        sg[3] = -ai * a3;
        sg[4] = d0 - ai * a1;
        sg[5] = -ai * a5;
        sg[6] = -ai * a4;
        sg[7] = -ai * a5;
        sg[8] = d0 - ai * a2;
        out_sg[g] = a6;
    }
}

extern "C" void kernel_launch(void* const* d_in, const int* in_sizes, int n_in,
                              void* d_out, int out_size, void* d_ws, size_t ws_size,
                              hipStream_t stream)
{
    const float* nf    = (const float*)d_in[0];
    const float* pos   = (const float*)d_in[1];
    const int*   ei    = (const int*)  d_in[2];
    const float* W_ai1 = (const float*)d_in[3];
    const float* b_ai1 = (const float*)d_in[4];
    const float* W_ai2 = (const float*)d_in[5];
    const float* b_ai2 = (const float*)d_in[6];
    const float* W_ci1 = (const float*)d_in[7];
    const float* b_ci1 = (const float*)d_in[8];
    const float* W_ci2 = (const float*)d_in[9];
    const float* b_ci2 = (const float*)d_in[10];
    const float* W_sc  = (const float*)d_in[11];
    const float* b_sc  = (const float*)d_in[12];
    const float* W_ed  = (const float*)d_in[13];
    const float* b_ed  = (const float*)d_in[14];
    const float* W_b1  = (const float*)d_in[15];
    const float* b_b1  = (const float*)d_in[16];
    const float* W_b2  = (const float*)d_in[17];
    const float* b_b2  = (const float*)d_in[18];

    // Byte-based bump allocator (256-B aligned).
    char* pb = (char*)d_ws;
    auto alloc = [&](size_t bytes) -> void* {
        void* r = (void*)pb;
        pb += (bytes + 255) & ~(size_t)255;
        return r;
    };
    float*          We      = (float*)         alloc(8192 * 4);
    float*          c0      = (float*)         alloc(256 * 4);
    _Float16*       Tab     = (_Float16*)      alloc((size_t)QTAB * 256 * 2);
    unsigned short* Bpack   = (unsigned short*)alloc((size_t)256 * 1024 * 2);
    unsigned short* scalp   = (unsigned short*)alloc((size_t)N_NODES * 256 * 2);
    _Float16*       u       = (_Float16*)      alloc((size_t)N_NODES * 256 * 2);
    _Float16*       v       = (_Float16*)      alloc((size_t)N_NODES * 256 * 2);
    float*          bsumseed= (float*)         alloc((size_t)N_NODES * 4);
    int*            cnt     = (int*)           alloc((size_t)N_NODES * 4);
    int*            startA  = (int*)           alloc((size_t)N_NODES * 4);
    int*            rank    = (int*)           alloc((size_t)E_EDGES * 4);
    int2*           sd      = (int2*)          alloc((size_t)E_EDGES * 8);
    float4*         geom    = (float4*)        alloc((size_t)E_EDGES * 16);
    float*          bijV    = (float*)         alloc((size_t)E_EDGES * 4);

    float* out       = (float*)d_out;
    float* out_sigma = out;                  // N*9
    float* out_ai    = out + N_NODES * 9;    // N
    float* out_sg    = out + N_NODES * 10;   // N

    prep_kernel<<<240, 256, 0, stream>>>(W_sc, W_ed, W_b1, b_sc, b_ed, b_b1, W_ai1, W_ci1,
                                         Bpack, We, c0, cnt);
    aux_kernel<<<8298, 256, 0, stream>>>(ei, cnt, rank, We, Tab, nf, scalp);
    mfma_scan_kernel<<<2501, 256, 0, stream>>>(scalp, Bpack, c0, b_ai1, W_ai2, b_ai2,
                                               b_ci1, W_ci2, b_ci2, u, v, bsumseed, out_ai,
                                               cnt, startA);
    edge_geom_kernel<<<1250, 256, 0, stream>>>(ei, startA, rank, pos, sd, geom);
    edge_bij_kernel<<<20000, 256, 0, stream>>>(sd, geom, u, v, Tab, W_b2, b_b2, bijV);
    node_reduce_kernel<<<1250, 256, 0, stream>>>(startA, cnt, bijV, geom, bsumseed, out_ai,
                                                 out_sigma, out_sg);
}

// Round 11
// 285.366 us; speedup vs baseline: 1.0295x; 1.0295x over previous
//
#include <hip/hip_runtime.h>
#include <math.h>

#define N_NODES 20000
#define E_EDGES 320000
#define F_DIM   960
#define S_DIM   256
#define QTAB    2048
#define ASTRIDE 264   // LDS A row stride in bf16 elems
#define CAP     64    // max deg per node (Poisson(16): P(deg>=64) ~ 2e-18)

typedef __attribute__((ext_vector_type(8))) short short8;
typedef __attribute__((ext_vector_type(4))) float f32x4;
typedef _Float16 half8 __attribute__((ext_vector_type(8)));

__device__ __forceinline__ float siluf(float x) {
    return x / (1.0f + __expf(-x));
}

__device__ __forceinline__ unsigned short bf16rn(float x) {
    unsigned u = __float_as_uint(x);
    return (unsigned short)((u + 0x7FFFu + ((u >> 16) & 1u)) >> 16);
}

// ---------------------------------------------------------------------------
// A: fold weights DIRECTLY into bf16 Bpack + We + c0 + zero cnt.
// Blocks: [0,128) fold->Bpack, [128,160) We, [160] c0, [161,240) cnt=0.
// ---------------------------------------------------------------------------
__global__ __launch_bounds__(256) void prep_kernel(
    const float* __restrict__ W_sc, const float* __restrict__ W_ed,
    const float* __restrict__ W_b1, const float* __restrict__ b_sc,
    const float* __restrict__ b_ed, const float* __restrict__ b_b1,
    const float* __restrict__ W_ai1, const float* __restrict__ W_ci1,
    unsigned short* __restrict__ Bpack, float* __restrict__ We, float* __restrict__ c0,
    int* __restrict__ cnt)
{
    const int b = blockIdx.x;
    const int tid = threadIdx.x;
    if (b < 128) {
        const int oct = b >> 2;                  // 0..31, uniform per block
        const int j   = (b & 3) * 256 + tid;     // 0..1023
        const int k0  = oct * 8;
        float s[8];
        #pragma unroll
        for (int jj = 0; jj < 8; ++jj) s[jj] = 0.0f;
        if (j < 256) {
            for (int m = 0; m < 256; ++m) {
                float wv = W_b1[m * 256 + j];
                #pragma unroll
                for (int jj = 0; jj < 8; ++jj) s[jj] += W_sc[(k0 + jj) * 256 + m] * wv;
            }
        } else if (j < 512) {
            const int j2 = j - 256;
            for (int m = 0; m < 256; ++m) {
                float wv = W_b1[(256 + m) * 256 + j2];
                #pragma unroll
                for (int jj = 0; jj < 8; ++jj) s[jj] += W_sc[(k0 + jj) * 256 + m] * wv;
            }
        } else if (j < 768) {
            #pragma unroll
            for (int jj = 0; jj < 8; ++jj) s[jj] = W_ai1[(k0 + jj) * 256 + (j - 512)];
        } else {
            #pragma unroll
            for (int jj = 0; jj < 8; ++jj) s[jj] = W_ci1[(k0 + jj) * 256 + (j - 768)];
        }
        unsigned short o[8];
        #pragma unroll
        for (int jj = 0; jj < 8; ++jj) o[jj] = bf16rn(s[jj]);
        unsigned short* dst = &Bpack[((oct >> 2) * 4096 + j * 4 + (oct & 3)) * 8];
        ushort4 lo; lo.x = o[0]; lo.y = o[1]; lo.z = o[2]; lo.w = o[3];
        ushort4 hi; hi.x = o[4]; hi.y = o[5]; hi.z = o[6]; hi.w = o[7];
        *(ushort4*)dst = lo;
        *(ushort4*)(dst + 4) = hi;
    } else if (b < 160) {
        const int t = (b - 128) * 256 + tid;     // 0..8191
        const int p = t >> 8, j = t & 255;
        float s = 0.0f;
        for (int m = 0; m < 256; ++m) s += W_ed[p * 256 + m] * W_b1[(512 + m) * 256 + j];
        We[t] = s;
    } else if (b == 160) {
        const int j = tid;
        float s = b_b1[j];
        for (int m = 0; m < 256; ++m) {
            s += b_sc[m] * (W_b1[m * 256 + j] + W_b1[(256 + m) * 256 + j]);
            s += b_ed[m] * W_b1[(512 + m) * 256 + j];
        }
        c0[j] = s;
    } else {
        const int idx = (b - 161) * 256 + tid;
        if (idx < N_NODES) cnt[idx] = 0;
    }
}

// ---------------------------------------------------------------------------
// B: fused rank-histogram + Tab(f16) + scal->bf16 pack (R8 structure).
// Blocks: [0,1250) rank, [1250,3298) table, [3298,8298) scalp.
// ---------------------------------------------------------------------------
__global__ void aux_kernel(const int* __restrict__ ei, int* __restrict__ cnt, int* __restrict__ rank,
                           const float* __restrict__ We, _Float16* __restrict__ Tab,
                           const float* __restrict__ nf, unsigned short* __restrict__ scalp)
{
    int b = blockIdx.x;
    if (b < 1250) {
        int i = b * 256 + threadIdx.x;          // 320000 exact
        rank[i] = atomicAdd(&cnt[ei[E_EDGES + i]], 1);
    } else if (b < 3298) {
        int idx = (b - 1250) * 256 + threadIdx.x;  // 524288 exact
        int q = idx >> 8, j = idx & 255;
        float nrm = 5.0f * (float)q / (float)(QTAB - 1);
        const float start = 0.006737946999085467f;  // exp(-5)
        const float mustep = (1.0f - start) / 31.0f;
        const float bx = (2.0f / 32.0f) * (1.0f - start);
        const float beta = 1.0f / (bx * bx);
        const float PI_F = 3.14159265358979323846f;
        float cc = (nrm < 5.0f) ? 0.5f * (__cosf(PI_F * nrm * 0.2f) + 1.0f) : 0.0f;
        float t = __expf(-nrm);
        float s = 0.0f;
        for (int k = 0; k < 32; ++k) {
            float dm = t - (start + (float)k * mustep);
            s += __expf(-beta * dm * dm) * We[k * 256 + j];
        }
        Tab[idx] = (_Float16)(cc * s);
    } else {
        int idx = (b - 3298) * 256 + threadIdx.x;  // 1.28M exact (x4 elems)
        int base = idx * 4;
        int n = base >> 8, k = base & 255;
        float4 a4 = *(const float4*)&nf[(size_t)n * F_DIM + k];
        ushort4 b4;
        b4.x = bf16rn(a4.x); b4.y = bf16rn(a4.y);
        b4.z = bf16rn(a4.z); b4.w = bf16rn(a4.w);
        *(ushort4*)&scalp[n * 256 + k] = b4;
    }
}

// C: one block, 1024 threads, 20 nodes/thread exclusive scan of cnt.
// Standalone ON PURPOSE: fusing into the GEMM launch (head R10 / tail R7)
// measured +8us / +15us vs this layout.
__global__ __launch_bounds__(1024) void scan_kernel(const int* __restrict__ cnt,
                                                    int* __restrict__ start)
{
    extern __shared__ int ls[];   // N_NODES ints = 80 KB
    __shared__ int ps[1024];
    const int t = threadIdx.x;
    for (int i = t; i < N_NODES; i += 1024) ls[i] = cnt[i];
    __syncthreads();

    const int base = t * 20;
    int loc[20];
    int s = 0;
    #pragma unroll
    for (int i = 0; i < 20; ++i) {
        int n = (base + i < N_NODES) ? ls[base + i] : 0;
        loc[i] = s; s += n;
    }
    ps[t] = s;
    __syncthreads();
    for (int off = 1; off < 1024; off <<= 1) {
        int v = (t >= off) ? ps[t - off] : 0;
        __syncthreads();
        ps[t] += v;
        __syncthreads();
    }
    int offset = ps[t] - s;   // exclusive
    #pragma unroll
    for (int i = 0; i < 20; ++i)
        if (base + i < N_NODES) ls[base + i] = offset + loc[i];
    __syncthreads();
    for (int i = t; i < N_NODES; i += 1024) start[i] = ls[i];
}

// ---------------------------------------------------------------------------
// E: node GEMM, R8 structure: BM=32, ONE col-group/block, 2500 blocks,
// 17 KB LDS, bf16 scalp staging. Pure GEMM.
// ---------------------------------------------------------------------------
__global__ __launch_bounds__(256) void node_mfma_kernel(
    const unsigned short* __restrict__ scalp, const unsigned short* __restrict__ Bpack,
    const float* __restrict__ c0,
    const float* __restrict__ b_ai1, const float* __restrict__ W_ai2, const float* __restrict__ b_ai2,
    const float* __restrict__ b_ci1, const float* __restrict__ W_ci2, const float* __restrict__ b_ci2,
    _Float16* __restrict__ u, _Float16* __restrict__ v,
    float* __restrict__ bsumseed, float* __restrict__ out_ai)
{
    __shared__ unsigned short A[32 * ASTRIDE];   // 16.9 KB
    __shared__ float red[32 * 4];

    const int tid = threadIdx.x;
    const int w = tid >> 6, lane = tid & 63;
    const int cg = blockIdx.x & 3;               // col-group 0..3
    const int m0 = (blockIdx.x >> 2) * 32;       // 625*32 = 20000 exact
    const int col16 = lane & 15, quad = lane >> 4;

    #pragma unroll
    for (int it = 0; it < 4; ++it) {
        int idx = (it * 256 + tid) * 8;          // bf16 elem 0..8191
        int r = idx >> 8, c = idx & 255;
        *(uint4*)&A[r * ASTRIDE + c] = *(const uint4*)&scalp[(size_t)(m0 + r) * 256 + c];
    }
    __syncthreads();

    f32x4 acc[2][4];
    #pragma unroll
    for (int mt = 0; mt < 2; ++mt)
        #pragma unroll
        for (int nt = 0; nt < 4; ++nt)
            acc[mt][nt] = (f32x4){0.0f, 0.0f, 0.0f, 0.0f};

    const int colbase = cg * 256 + w * 64;

    for (int t = 0; t < 8; ++t) {
        short8 af[2];
        #pragma unroll
        for (int mt = 0; mt < 2; ++mt)
            af[mt] = *(const short8*)&A[(mt * 16 + col16) * ASTRIDE + t * 32 + quad * 8];
        short8 bf[4];
        #pragma unroll
        for (int nt = 0; nt < 4; ++nt)
            bf[nt] = *(const short8*)&Bpack[(((t * 1024 + colbase + nt * 16 + col16) * 4) + quad) * 8];
        #pragma unroll
        for (int mt = 0; mt < 2; ++mt)
            #pragma unroll
            for (int nt = 0; nt < 4; ++nt)
                acc[mt][nt] = __builtin_amdgcn_mfma_f32_16x16x32_bf16(af[mt], bf[nt], acc[mt][nt], 0, 0, 0);
    }

    if (cg == 0) {
        #pragma unroll
        for (int nt = 0; nt < 4; ++nt) {
            int jl = w * 64 + nt * 16 + col16;
            float c0v = c0[jl];
            #pragma unroll
            for (int mt = 0; mt < 2; ++mt)
                #pragma unroll
                for (int reg = 0; reg < 4; ++reg)
                    u[(size_t)(m0 + mt * 16 + quad * 4 + reg) * 256 + jl] = (_Float16)(acc[mt][nt][reg] + c0v);
        }
    } else if (cg == 1) {
        #pragma unroll
        for (int nt = 0; nt < 4; ++nt) {
            int jl = w * 64 + nt * 16 + col16;
            #pragma unroll
            for (int mt = 0; mt < 2; ++mt)
                #pragma unroll
                for (int reg = 0; reg < 4; ++reg)
                    v[(size_t)(m0 + mt * 16 + quad * 4 + reg) * 256 + jl] = (_Float16)(acc[mt][nt][reg]);
        }
    } else {
        const float* b1 = (cg == 2) ? b_ai1 : b_ci1;
        const float* w2 = (cg == 2) ? W_ai2 : W_ci2;
        float s[2][4] = {{0, 0, 0, 0}, {0, 0, 0, 0}};
        #pragma unroll
        for (int nt = 0; nt < 4; ++nt) {
            int jl = w * 64 + nt * 16 + col16;
            float bb = b1[jl], ww = w2[jl];
            #pragma unroll
            for (int mt = 0; mt < 2; ++mt)
                #pragma unroll
                for (int reg = 0; reg < 4; ++reg)
                    s[mt][reg] += siluf(acc[mt][nt][reg] + bb) * ww;
        }
        #pragma unroll
        for (int off = 1; off < 16; off <<= 1) {
            #pragma unroll
            for (int mt = 0; mt < 2; ++mt)
                #pragma unroll
                for (int reg = 0; reg < 4; ++reg)
                    s[mt][reg] += __shfl_xor(s[mt][reg], off);
        }
        if (col16 == 0) {
            #pragma unroll
            for (int mt = 0; mt < 2; ++mt)
                #pragma unroll
                for (int reg = 0; reg < 4; ++reg)
                    red[(mt * 16 + quad * 4 + reg) * 4 + w] = s[mt][reg];
        }
        __syncthreads();
        if (tid < 32) {
            float sum = red[tid * 4] + red[tid * 4 + 1] + red[tid * 4 + 2] + red[tid * 4 + 3];
            if (cg == 2) out_ai[m0 + tid] = expf(sum + b_ai2[0]);
            else         bsumseed[m0 + tid] = expf(sum + b_ci2[0]) + 1e-7f;  // ci + eps
        }
    }
}

// ---------------------------------------------------------------------------
// D: per-edge geometry + CSR scatter. geom[slot] = {rx, ry, rz, x}.
// ---------------------------------------------------------------------------
__global__ void edge_geom_kernel(const int* __restrict__ ei, const int* __restrict__ start,
                                 const int* __restrict__ rank, const float* __restrict__ pos,
                                 int2* __restrict__ sd, float4* __restrict__ geom)
{
    int i = blockIdx.x * 256 + threadIdx.x;
    if (i >= E_EDGES) return;
    int s = ei[i];
    int d = ei[E_EDGES + i];
    int slot = start[d] + rank[i];
    int2 p; p.x = s; p.y = d;
    sd[slot] = p;

    // rel = pos[dst] - pos[src]  (matches reference)
    float px = pos[3 * d + 0] - pos[3 * s + 0];
    float py = pos[3 * d + 1] - pos[3 * s + 1];
    float pz = pos[3 * d + 2] - pos[3 * s + 2];
    float nrm = sqrtf(px * px + py * py + pz * pz);
    float inv = 1.0f / (nrm + 1e-8f);
    float4 o;
    o.x = px * inv; o.y = py * inv; o.z = pz * inv;
    o.w = nrm * (float)(QTAB - 1) * 0.2f;
    geom[slot] = o;
}

// ---------------------------------------------------------------------------
// F1: edge-parallel MLP, TWO slots per 16-lane group (2x memory-level
// parallelism: 16 independent gathers in flight before any dependent math).
// 10000 blocks x 16 groups x 2 slots = 320000 exact. Static _0/_1 naming.
// ---------------------------------------------------------------------------
__global__ __launch_bounds__(256) void edge_bij_kernel(
    const int2* __restrict__ sd, const float4* __restrict__ geom,
    const _Float16* __restrict__ u, const _Float16* __restrict__ v,
    const _Float16* __restrict__ Tab,
    const float* __restrict__ W_b2, const float* __restrict__ b_b2,
    float* __restrict__ bijV)
{
    const int l = threadIdx.x & 15;
    const int grp = threadIdx.x >> 4;
    const int slot0 = blockIdx.x * 32 + grp * 2;

    const int2 e0 = sd[slot0];
    const int2 e1 = sd[slot0 + 1];
    const float x0 = ((const float*)&geom[slot0])[3];
    const float x1 = ((const float*)&geom[slot0 + 1])[3];

    int qi0 = (int)x0;
    float f0 = x0 - (float)qi0;
    if (qi0 >= QTAB - 1) { qi0 = QTAB - 2; f0 = 1.0f; }
    int qi1 = (int)x1;
    float f1 = x1 - (float)qi1;
    if (qi1 >= QTAB - 1) { qi1 = QTAB - 2; f1 = 1.0f; }
    const _Float16 fh0 = (_Float16)f0;
    const _Float16 fh1 = (_Float16)f1;

    float w2c[16];
    #pragma unroll
    for (int c = 0; c < 16; c += 4)
        *(float4*)&w2c[c] = *(const float4*)&W_b2[l * 16 + c];

    // 32-bit byte offsets (rows are 512 B).
    const unsigned lo = (unsigned)l * 32u;
    const char* ub0 = (const char*)u + ((unsigned)e0.x * 512u + lo);
    const char* vb0 = (const char*)v + ((unsigned)e0.y * 512u + lo);
    const char* tb0 = (const char*)Tab + ((unsigned)qi0 * 512u + lo);
    const char* ub1 = (const char*)u + ((unsigned)e1.x * 512u + lo);
    const char* vb1 = (const char*)v + ((unsigned)e1.y * 512u + lo);
    const char* tb1 = (const char*)Tab + ((unsigned)qi1 * 512u + lo);

    // All 16 independent gathers issued up front.
    half8 u00 = *(const half8*)(ub0);
    half8 u01 = *(const half8*)(ub0 + 16);
    half8 v00 = *(const half8*)(vb0);
    half8 v01 = *(const half8*)(vb0 + 16);
    half8 ta0 = *(const half8*)(tb0);
    half8 tb0a = *(const half8*)(tb0 + 16);
    half8 tc0 = *(const half8*)(tb0 + 512);
    half8 td0 = *(const half8*)(tb0 + 528);
    half8 u10 = *(const half8*)(ub1);
    half8 u11 = *(const half8*)(ub1 + 16);
    half8 v10 = *(const half8*)(vb1);
    half8 v11 = *(const half8*)(vb1 + 16);
    half8 ta1 = *(const half8*)(tb1);
    half8 tb1a = *(const half8*)(tb1 + 16);
    half8 tc1 = *(const half8*)(tb1 + 512);
    half8 td1 = *(const half8*)(tb1 + 528);

    half8 h00 = (u00 + v00) + (ta0 + fh0 * (tc0 - ta0));
    half8 h01 = (u01 + v01) + (tb0a + fh0 * (td0 - tb0a));
    half8 h10 = (u10 + v10) + (ta1 + fh1 * (tc1 - ta1));
    half8 h11 = (u11 + v11) + (tb1a + fh1 * (td1 - tb1a));

    float acc0 = 0.0f, acc1 = 0.0f;
    #pragma unroll
    for (int c = 0; c < 8; ++c) {
        float hf0 = (float)h00[c];
        acc0 += w2c[c] * hf0 * __builtin_amdgcn_rcpf(1.0f + __expf(-hf0));
        float hf1 = (float)h10[c];
        acc1 += w2c[c] * hf1 * __builtin_amdgcn_rcpf(1.0f + __expf(-hf1));
    }
    #pragma unroll
    for (int c = 0; c < 8; ++c) {
        float hf0 = (float)h01[c];
        acc0 += w2c[8 + c] * hf0 * __builtin_amdgcn_rcpf(1.0f + __expf(-hf0));
        float hf1 = (float)h11[c];
        acc1 += w2c[8 + c] * hf1 * __builtin_amdgcn_rcpf(1.0f + __expf(-hf1));
    }
    #pragma unroll
    for (int off = 1; off < 16; off <<= 1) {
        acc0 += __shfl_xor(acc0, off);
        acc1 += __shfl_xor(acc1, off);
    }

    if (l == 0) {
        float2 o;
        o.x = acc0 + b_b2[0];
        o.y = acc1 + b_b2[0];
        *(float2*)&bijV[slot0] = o;
    }
}

// ---------------------------------------------------------------------------
// F2: node-parallel softmax + outer-product. 16 lanes/node, CSR segment kept
// entirely in registers (CAP=64 -> 4 slots/lane, statically indexed).
// ---------------------------------------------------------------------------
__global__ __launch_bounds__(256) void node_reduce_kernel(
    const int* __restrict__ start, const int* __restrict__ cnt,
    const float* __restrict__ bijV, const float4* __restrict__ geom,
    const float* __restrict__ bsumseed, const float* __restrict__ out_ai,
    float* __restrict__ out_sigma, float* __restrict__ out_sg)
{
    const int grp = threadIdx.x >> 4;
    const int l = threadIdx.x & 15;
    const int g = blockIdx.x * 16 + grp;   // 1250*16 = 20000 exact
    const int st = start[g];
    const int deg = min(cnt[g], CAP);

    float bj[4], ex[4], ey[4], ez[4];
    bool ok[4];
    float m = -1e30f;
    #pragma unroll
    for (int k = 0; k < 4; ++k) {
        int i = l + k * 16;
        ok[k] = (i < deg);
        if (ok[k]) {
            float4 o = geom[st + i];
            bj[k] = bijV[st + i];
            ex[k] = o.x; ey[k] = o.y; ez[k] = o.z;
        } else {
            bj[k] = -1e30f; ex[k] = 0.0f; ey[k] = 0.0f; ez[k] = 0.0f;
        }
        m = fmaxf(m, bj[k]);
    }
    #pragma unroll
    for (int off = 1; off < 16; off <<= 1) m = fmaxf(m, __shfl_xor(m, off));

    float g4[4];
    float ssum = 0.0f;
    #pragma unroll
    for (int k = 0; k < 4; ++k) {
        g4[k] = ok[k] ? __expf(bj[k] - m) : 0.0f;
        ssum += g4[k];
    }
    #pragma unroll
    for (int off = 1; off < 16; off <<= 1) ssum += __shfl_xor(ssum, off);

    float invt = 1.0f / (ssum + bsumseed[g]);   // seed = ci + 1e-7

    float a0 = 0, a1 = 0, a2 = 0, a3 = 0, a4 = 0, a5 = 0, a6 = 0;
    #pragma unroll
    for (int k = 0; k < 4; ++k) {
        float gm = g4[k] * invt;
        a0 += gm * ex[k] * ex[k]; a1 += gm * ey[k] * ey[k]; a2 += gm * ez[k] * ez[k];
        a3 += gm * ex[k] * ey[k]; a4 += gm * ex[k] * ez[k]; a5 += gm * ey[k] * ez[k];
        a6 += gm;
    }
    #pragma unroll
    for (int off = 1; off < 16; off <<= 1) {
        a0 += __shfl_xor(a0, off); a1 += __shfl_xor(a1, off);
        a2 += __shfl_xor(a2, off); a3 += __shfl_xor(a3, off);
        a4 += __shfl_xor(a4, off); a5 += __shfl_xor(a5, off);
        a6 += __shfl_xor(a6, off);
    }

    if (l == 0) {
        float ai = out_ai[g];
        float* sg = &out_sigma[g * 9];
        float d0 = ai + 1e-6f;
        sg[0] = d0 - ai * a0;
        sg[1] = -ai * a3;
        sg[2] = -ai * a4;
        sg[3] = -ai * a3;
        sg[4] = d0 - ai * a1;
        sg[5] = -ai * a5;
        sg[6] = -ai * a4;
        sg[7] = -ai * a5;
        sg[8] = d0 - ai * a2;
        out_sg[g] = a6;
    }
}

extern "C" void kernel_launch(void* const* d_in, const int* in_sizes, int n_in,
                              void* d_out, int out_size, void* d_ws, size_t ws_size,
                              hipStream_t stream)
{
    const float* nf    = (const float*)d_in[0];
    const float* pos   = (const float*)d_in[1];
    const int*   ei    = (const int*)  d_in[2];
    const float* W_ai1 = (const float*)d_in[3];
    const float* b_ai1 = (const float*)d_in[4];
    const float* W_ai2 = (const float*)d_in[5];
    const float* b_ai2 = (const float*)d_in[6];
    const float* W_ci1 = (const float*)d_in[7];
    const float* b_ci1 = (const float*)d_in[8];
    const float* W_ci2 = (const float*)d_in[9];
    const float* b_ci2 = (const float*)d_in[10];
    const float* W_sc  = (const float*)d_in[11];
    const float* b_sc  = (const float*)d_in[12];
    const float* W_ed  = (const float*)d_in[13];
    const float* b_ed  = (const float*)d_in[14];
    const float* W_b1  = (const float*)d_in[15];
    const float* b_b1  = (const float*)d_in[16];
    const float* W_b2  = (const float*)d_in[17];
    const float* b_b2  = (const float*)d_in[18];

    // Byte-based bump allocator (256-B aligned).
    char* pb = (char*)d_ws;
    auto alloc = [&](size_t bytes) -> void* {
        void* r = (void*)pb;
        pb += (bytes + 255) & ~(size_t)255;
        return r;
    };
    float*          We      = (float*)         alloc(8192 * 4);
    float*          c0      = (float*)         alloc(256 * 4);
    _Float16*       Tab     = (_Float16*)      alloc((size_t)QTAB * 256 * 2);
    unsigned short* Bpack   = (unsigned short*)alloc((size_t)256 * 1024 * 2);
    unsigned short* scalp   = (unsigned short*)alloc((size_t)N_NODES * 256 * 2);
    _Float16*       u       = (_Float16*)      alloc((size_t)N_NODES * 256 * 2);
    _Float16*       v       = (_Float16*)      alloc((size_t)N_NODES * 256 * 2);
    float*          bsumseed= (float*)         alloc((size_t)N_NODES * 4);
    int*            cnt     = (int*)           alloc((size_t)N_NODES * 4);
    int*            startA  = (int*)           alloc((size_t)N_NODES * 4);
    int*            rank    = (int*)           alloc((size_t)E_EDGES * 4);
    int2*           sd      = (int2*)          alloc((size_t)E_EDGES * 8);
    float4*         geom    = (float4*)        alloc((size_t)E_EDGES * 16);
    float*          bijV    = (float*)         alloc((size_t)E_EDGES * 4);

    float* out       = (float*)d_out;
    float* out_sigma = out;                  // N*9
    float* out_ai    = out + N_NODES * 9;    // N
    float* out_sg    = out + N_NODES * 10;   // N

    prep_kernel<<<240, 256, 0, stream>>>(W_sc, W_ed, W_b1, b_sc, b_ed, b_b1, W_ai1, W_ci1,
                                         Bpack, We, c0, cnt);
    aux_kernel<<<8298, 256, 0, stream>>>(ei, cnt, rank, We, Tab, nf, scalp);
    scan_kernel<<<1, 1024, (size_t)N_NODES * 4, stream>>>(cnt, startA);
    node_mfma_kernel<<<2500, 256, 0, stream>>>(scalp, Bpack, c0, b_ai1, W_ai2, b_ai2,
                                               b_ci1, W_ci2, b_ci2, u, v, bsumseed, out_ai);
    edge_geom_kernel<<<1250, 256, 0, stream>>>(ei, startA, rank, pos, sd, geom);
    edge_bij_kernel<<<10000, 256, 0, stream>>>(sd, geom, u, v, Tab, W_b2, b_b2, bijV);
    node_reduce_kernel<<<1250, 256, 0, stream>>>(startA, cnt, bijV, geom, bsumseed, out_ai,
                                                 out_sigma, out_sg);
}

// Round 12
// 279.710 us; speedup vs baseline: 1.0504x; 1.0202x over previous
//
#include <hip/hip_runtime.h>
#include <math.h>

#define N_NODES 20000
#define E_EDGES 320000
#define F_DIM   960
#define S_DIM   256
#define QTAB    2048
#define ASTRIDE 264   // LDS A row stride in bf16 elems
#define CAP     64    // max deg per node (Poisson(16): P(deg>=64) ~ 2e-18)

typedef __attribute__((ext_vector_type(8))) short short8;
typedef __attribute__((ext_vector_type(4))) float f32x4;
typedef _Float16 half8 __attribute__((ext_vector_type(8)));

__device__ __forceinline__ float siluf(float x) {
    return x / (1.0f + __expf(-x));
}

__device__ __forceinline__ unsigned short bf16rn(float x) {
    unsigned u = __float_as_uint(x);
    return (unsigned short)((u + 0x7FFFu + ((u >> 16) & 1u)) >> 16);
}

// ---------------------------------------------------------------------------
// A: fold weights DIRECTLY into bf16 Bpack + We + c0 + zero cnt.
// Blocks: [0,128) fold->Bpack, [128,160) We, [160] c0, [161,240) cnt=0.
// ---------------------------------------------------------------------------
__global__ __launch_bounds__(256) void prep_kernel(
    const float* __restrict__ W_sc, const float* __restrict__ W_ed,
    const float* __restrict__ W_b1, const float* __restrict__ b_sc,
    const float* __restrict__ b_ed, const float* __restrict__ b_b1,
    const float* __restrict__ W_ai1, const float* __restrict__ W_ci1,
    unsigned short* __restrict__ Bpack, float* __restrict__ We, float* __restrict__ c0,
    int* __restrict__ cnt)
{
    const int b = blockIdx.x;
    const int tid = threadIdx.x;
    if (b < 128) {
        const int oct = b >> 2;                  // 0..31, uniform per block
        const int j   = (b & 3) * 256 + tid;     // 0..1023
        const int k0  = oct * 8;
        float s[8];
        #pragma unroll
        for (int jj = 0; jj < 8; ++jj) s[jj] = 0.0f;
        if (j < 256) {
            for (int m = 0; m < 256; ++m) {
                float wv = W_b1[m * 256 + j];
                #pragma unroll
                for (int jj = 0; jj < 8; ++jj) s[jj] += W_sc[(k0 + jj) * 256 + m] * wv;
            }
        } else if (j < 512) {
            const int j2 = j - 256;
            for (int m = 0; m < 256; ++m) {
                float wv = W_b1[(256 + m) * 256 + j2];
                #pragma unroll
                for (int jj = 0; jj < 8; ++jj) s[jj] += W_sc[(k0 + jj) * 256 + m] * wv;
            }
        } else if (j < 768) {
            #pragma unroll
            for (int jj = 0; jj < 8; ++jj) s[jj] = W_ai1[(k0 + jj) * 256 + (j - 512)];
        } else {
            #pragma unroll
            for (int jj = 0; jj < 8; ++jj) s[jj] = W_ci1[(k0 + jj) * 256 + (j - 768)];
        }
        unsigned short o[8];
        #pragma unroll
        for (int jj = 0; jj < 8; ++jj) o[jj] = bf16rn(s[jj]);
        unsigned short* dst = &Bpack[((oct >> 2) * 4096 + j * 4 + (oct & 3)) * 8];
        ushort4 lo; lo.x = o[0]; lo.y = o[1]; lo.z = o[2]; lo.w = o[3];
        ushort4 hi; hi.x = o[4]; hi.y = o[5]; hi.z = o[6]; hi.w = o[7];
        *(ushort4*)dst = lo;
        *(ushort4*)(dst + 4) = hi;
    } else if (b < 160) {
        const int t = (b - 128) * 256 + tid;     // 0..8191
        const int p = t >> 8, j = t & 255;
        float s = 0.0f;
        for (int m = 0; m < 256; ++m) s += W_ed[p * 256 + m] * W_b1[(512 + m) * 256 + j];
        We[t] = s;
    } else if (b == 160) {
        const int j = tid;
        float s = b_b1[j];
        for (int m = 0; m < 256; ++m) {
            s += b_sc[m] * (W_b1[m * 256 + j] + W_b1[(256 + m) * 256 + j]);
            s += b_ed[m] * W_b1[(512 + m) * 256 + j];
        }
        c0[j] = s;
    } else {
        const int idx = (b - 161) * 256 + tid;
        if (idx < N_NODES) cnt[idx] = 0;
    }
}

// ---------------------------------------------------------------------------
// B: fused rank-histogram + Tab(f16) + scal->bf16 pack (R8 structure).
// Blocks: [0,1250) rank, [1250,3298) table, [3298,8298) scalp.
// ---------------------------------------------------------------------------
__global__ void aux_kernel(const int* __restrict__ ei, int* __restrict__ cnt, int* __restrict__ rank,
                           const float* __restrict__ We, _Float16* __restrict__ Tab,
                           const float* __restrict__ nf, unsigned short* __restrict__ scalp)
{
    int b = blockIdx.x;
    if (b < 1250) {
        int i = b * 256 + threadIdx.x;          // 320000 exact
        rank[i] = atomicAdd(&cnt[ei[E_EDGES + i]], 1);
    } else if (b < 3298) {
        int idx = (b - 1250) * 256 + threadIdx.x;  // 524288 exact
        int q = idx >> 8, j = idx & 255;
        float nrm = 5.0f * (float)q / (float)(QTAB - 1);
        const float start = 0.006737946999085467f;  // exp(-5)
        const float mustep = (1.0f - start) / 31.0f;
        const float bx = (2.0f / 32.0f) * (1.0f - start);
        const float beta = 1.0f / (bx * bx);
        const float PI_F = 3.14159265358979323846f;
        float cc = (nrm < 5.0f) ? 0.5f * (__cosf(PI_F * nrm * 0.2f) + 1.0f) : 0.0f;
        float t = __expf(-nrm);
        float s = 0.0f;
        for (int k = 0; k < 32; ++k) {
            float dm = t - (start + (float)k * mustep);
            s += __expf(-beta * dm * dm) * We[k * 256 + j];
        }
        Tab[idx] = (_Float16)(cc * s);
    } else {
        int idx = (b - 3298) * 256 + threadIdx.x;  // 1.28M exact (x4 elems)
        int base = idx * 4;
        int n = base >> 8, k = base & 255;
        float4 a4 = *(const float4*)&nf[(size_t)n * F_DIM + k];
        ushort4 b4;
        b4.x = bf16rn(a4.x); b4.y = bf16rn(a4.y);
        b4.z = bf16rn(a4.z); b4.w = bf16rn(a4.w);
        *(ushort4*)&scalp[n * 256 + k] = b4;
    }
}

// C: one block, 1024 threads, 20 nodes/thread exclusive scan of cnt.
// Standalone ON PURPOSE: fusing into the GEMM launch (head R10 / tail R7)
// measured +8us / +15us vs this layout.
__global__ __launch_bounds__(1024) void scan_kernel(const int* __restrict__ cnt,
                                                    int* __restrict__ start)
{
    extern __shared__ int ls[];   // N_NODES ints = 80 KB
    __shared__ int ps[1024];
    const int t = threadIdx.x;
    for (int i = t; i < N_NODES; i += 1024) ls[i] = cnt[i];
    __syncthreads();

    const int base = t * 20;
    int loc[20];
    int s = 0;
    #pragma unroll
    for (int i = 0; i < 20; ++i) {
        int n = (base + i < N_NODES) ? ls[base + i] : 0;
        loc[i] = s; s += n;
    }
    ps[t] = s;
    __syncthreads();
    for (int off = 1; off < 1024; off <<= 1) {
        int v = (t >= off) ? ps[t - off] : 0;
        __syncthreads();
        ps[t] += v;
        __syncthreads();
    }
    int offset = ps[t] - s;   // exclusive
    #pragma unroll
    for (int i = 0; i < 20; ++i)
        if (base + i < N_NODES) ls[base + i] = offset + loc[i];
    __syncthreads();
    for (int i = t; i < N_NODES; i += 1024) start[i] = ls[i];
}

// ---------------------------------------------------------------------------
// E: node GEMM, R8 structure (BM=32, ONE col-group/block, 2500 blocks)
// + NEW: 2-stage register double-buffer for B. R7 counters showed the GEMM
// latency-bound (Occ 18%, VALU 13%, FETCH 20MB) with VGPR=56 proving the
// compiler issues the 4 B-loads inside each K-step (8 serial L2 round
// trips). Prefetch t+1's B before t's LDS reads/MFMAs; fully unrolled.
// ---------------------------------------------------------------------------
__global__ __launch_bounds__(256) void node_mfma_kernel(
    const unsigned short* __restrict__ scalp, const unsigned short* __restrict__ Bpack,
    const float* __restrict__ c0,
    const float* __restrict__ b_ai1, const float* __restrict__ W_ai2, const float* __restrict__ b_ai2,
    const float* __restrict__ b_ci1, const float* __restrict__ W_ci2, const float* __restrict__ b_ci2,
    _Float16* __restrict__ u, _Float16* __restrict__ v,
    float* __restrict__ bsumseed, float* __restrict__ out_ai)
{
    __shared__ unsigned short A[32 * ASTRIDE];   // 16.9 KB
    __shared__ float red[32 * 4];

    const int tid = threadIdx.x;
    const int w = tid >> 6, lane = tid & 63;
    const int cg = blockIdx.x & 3;               // col-group 0..3
    const int m0 = (blockIdx.x >> 2) * 32;       // 625*32 = 20000 exact
    const int col16 = lane & 15, quad = lane >> 4;

    #pragma unroll
    for (int it = 0; it < 4; ++it) {
        int idx = (it * 256 + tid) * 8;          // bf16 elem 0..8191
        int r = idx >> 8, c = idx & 255;
        *(uint4*)&A[r * ASTRIDE + c] = *(const uint4*)&scalp[(size_t)(m0 + r) * 256 + c];
    }

    // Per-lane B base: addr(t,nt) = bp + t*32768 + nt*512 (elems).
    const int colbase = cg * 256 + w * 64;
    const unsigned short* bp = Bpack + ((size_t)(colbase + col16) * 4 + quad) * 8;

    // Prefetch t=0's B while A staging is in flight (no barrier yet).
    short8 bf_c[4];
    #pragma unroll
    for (int nt = 0; nt < 4; ++nt)
        bf_c[nt] = *(const short8*)(bp + nt * 512);

    __syncthreads();

    f32x4 acc[2][4];
    #pragma unroll
    for (int mt = 0; mt < 2; ++mt)
        #pragma unroll
        for (int nt = 0; nt < 4; ++nt)
            acc[mt][nt] = (f32x4){0.0f, 0.0f, 0.0f, 0.0f};

    #pragma unroll
    for (int t = 0; t < 8; ++t) {
        short8 bf_n[4];
        if (t < 7) {
            #pragma unroll
            for (int nt = 0; nt < 4; ++nt)
                bf_n[nt] = *(const short8*)(bp + (t + 1) * 32768 + nt * 512);
        }
        short8 af[2];
        #pragma unroll
        for (int mt = 0; mt < 2; ++mt)
            af[mt] = *(const short8*)&A[(mt * 16 + col16) * ASTRIDE + t * 32 + quad * 8];
        #pragma unroll
        for (int mt = 0; mt < 2; ++mt)
            #pragma unroll
            for (int nt = 0; nt < 4; ++nt)
                acc[mt][nt] = __builtin_amdgcn_mfma_f32_16x16x32_bf16(af[mt], bf_c[nt], acc[mt][nt], 0, 0, 0);
        if (t < 7) {
            #pragma unroll
            for (int nt = 0; nt < 4; ++nt) bf_c[nt] = bf_n[nt];
        }
    }

    if (cg == 0) {
        #pragma unroll
        for (int nt = 0; nt < 4; ++nt) {
            int jl = w * 64 + nt * 16 + col16;
            float c0v = c0[jl];
            #pragma unroll
            for (int mt = 0; mt < 2; ++mt)
                #pragma unroll
                for (int reg = 0; reg < 4; ++reg)
                    u[(size_t)(m0 + mt * 16 + quad * 4 + reg) * 256 + jl] = (_Float16)(acc[mt][nt][reg] + c0v);
        }
    } else if (cg == 1) {
        #pragma unroll
        for (int nt = 0; nt < 4; ++nt) {
            int jl = w * 64 + nt * 16 + col16;
            #pragma unroll
            for (int mt = 0; mt < 2; ++mt)
                #pragma unroll
                for (int reg = 0; reg < 4; ++reg)
                    v[(size_t)(m0 + mt * 16 + quad * 4 + reg) * 256 + jl] = (_Float16)(acc[mt][nt][reg]);
        }
    } else {
        const float* b1 = (cg == 2) ? b_ai1 : b_ci1;
        const float* w2 = (cg == 2) ? W_ai2 : W_ci2;
        float s[2][4] = {{0, 0, 0, 0}, {0, 0, 0, 0}};
        #pragma unroll
        for (int nt = 0; nt < 4; ++nt) {
            int jl = w * 64 + nt * 16 + col16;
            float bb = b1[jl], ww = w2[jl];
            #pragma unroll
            for (int mt = 0; mt < 2; ++mt)
                #pragma unroll
                for (int reg = 0; reg < 4; ++reg)
                    s[mt][reg] += siluf(acc[mt][nt][reg] + bb) * ww;
        }
        #pragma unroll
        for (int off = 1; off < 16; off <<= 1) {
            #pragma unroll
            for (int mt = 0; mt < 2; ++mt)
                #pragma unroll
                for (int reg = 0; reg < 4; ++reg)
                    s[mt][reg] += __shfl_xor(s[mt][reg], off);
        }
        if (col16 == 0) {
            #pragma unroll
            for (int mt = 0; mt < 2; ++mt)
                #pragma unroll
                for (int reg = 0; reg < 4; ++reg)
                    red[(mt * 16 + quad * 4 + reg) * 4 + w] = s[mt][reg];
        }
        __syncthreads();
        if (tid < 32) {
            float sum = red[tid * 4] + red[tid * 4 + 1] + red[tid * 4 + 2] + red[tid * 4 + 3];
            if (cg == 2) out_ai[m0 + tid] = expf(sum + b_ai2[0]);
            else         bsumseed[m0 + tid] = expf(sum + b_ci2[0]) + 1e-7f;  // ci + eps
        }
    }
}

// ---------------------------------------------------------------------------
// D: per-edge geometry + CSR scatter. geom[slot] = {rx, ry, rz, x}.
// ---------------------------------------------------------------------------
__global__ void edge_geom_kernel(const int* __restrict__ ei, const int* __restrict__ start,
                                 const int* __restrict__ rank, const float* __restrict__ pos,
                                 int2* __restrict__ sd, float4* __restrict__ geom)
{
    int i = blockIdx.x * 256 + threadIdx.x;
    if (i >= E_EDGES) return;
    int s = ei[i];
    int d = ei[E_EDGES + i];
    int slot = start[d] + rank[i];
    int2 p; p.x = s; p.y = d;
    sd[slot] = p;

    // rel = pos[dst] - pos[src]  (matches reference)
    float px = pos[3 * d + 0] - pos[3 * s + 0];
    float py = pos[3 * d + 1] - pos[3 * s + 1];
    float pz = pos[3 * d + 2] - pos[3 * s + 2];
    float nrm = sqrtf(px * px + py * py + pz * pz);
    float inv = 1.0f / (nrm + 1e-8f);
    float4 o;
    o.x = px * inv; o.y = py * inv; o.z = pz * inv;
    o.w = nrm * (float)(QTAB - 1) * 0.2f;
    geom[slot] = o;
}

// ---------------------------------------------------------------------------
// F1: edge-parallel MLP, TWO slots per 16-lane group (2x memory-level
// parallelism). 10000 blocks x 16 groups x 2 slots = 320000 exact.
// ---------------------------------------------------------------------------
__global__ __launch_bounds__(256) void edge_bij_kernel(
    const int2* __restrict__ sd, const float4* __restrict__ geom,
    const _Float16* __restrict__ u, const _Float16* __restrict__ v,
    const _Float16* __restrict__ Tab,
    const float* __restrict__ W_b2, const float* __restrict__ b_b2,
    float* __restrict__ bijV)
{
    const int l = threadIdx.x & 15;
    const int grp = threadIdx.x >> 4;
    const int slot0 = blockIdx.x * 32 + grp * 2;

    const int2 e0 = sd[slot0];
    const int2 e1 = sd[slot0 + 1];
    const float x0 = ((const float*)&geom[slot0])[3];
    const float x1 = ((const float*)&geom[slot0 + 1])[3];

    int qi0 = (int)x0;
    float f0 = x0 - (float)qi0;
    if (qi0 >= QTAB - 1) { qi0 = QTAB - 2; f0 = 1.0f; }
    int qi1 = (int)x1;
    float f1 = x1 - (float)qi1;
    if (qi1 >= QTAB - 1) { qi1 = QTAB - 2; f1 = 1.0f; }
    const _Float16 fh0 = (_Float16)f0;
    const _Float16 fh1 = (_Float16)f1;

    float w2c[16];
    #pragma unroll
    for (int c = 0; c < 16; c += 4)
        *(float4*)&w2c[c] = *(const float4*)&W_b2[l * 16 + c];

    // 32-bit byte offsets (rows are 512 B).
    const unsigned lo = (unsigned)l * 32u;
    const char* ub0 = (const char*)u + ((unsigned)e0.x * 512u + lo);
    const char* vb0 = (const char*)v + ((unsigned)e0.y * 512u + lo);
    const char* tb0 = (const char*)Tab + ((unsigned)qi0 * 512u + lo);
    const char* ub1 = (const char*)u + ((unsigned)e1.x * 512u + lo);
    const char* vb1 = (const char*)v + ((unsigned)e1.y * 512u + lo);
    const char* tb1 = (const char*)Tab + ((unsigned)qi1 * 512u + lo);

    // All 16 independent gathers issued up front.
    half8 u00 = *(const half8*)(ub0);
    half8 u01 = *(const half8*)(ub0 + 16);
    half8 v00 = *(const half8*)(vb0);
    half8 v01 = *(const half8*)(vb0 + 16);
    half8 ta0 = *(const half8*)(tb0);
    half8 tb0a = *(const half8*)(tb0 + 16);
    half8 tc0 = *(const half8*)(tb0 + 512);
    half8 td0 = *(const half8*)(tb0 + 528);
    half8 u10 = *(const half8*)(ub1);
    half8 u11 = *(const half8*)(ub1 + 16);
    half8 v10 = *(const half8*)(vb1);
    half8 v11 = *(const half8*)(vb1 + 16);
    half8 ta1 = *(const half8*)(tb1);
    half8 tb1a = *(const half8*)(tb1 + 16);
    half8 tc1 = *(const half8*)(tb1 + 512);
    half8 td1 = *(const half8*)(tb1 + 528);

    half8 h00 = (u00 + v00) + (ta0 + fh0 * (tc0 - ta0));
    half8 h01 = (u01 + v01) + (tb0a + fh0 * (td0 - tb0a));
    half8 h10 = (u10 + v10) + (ta1 + fh1 * (tc1 - ta1));
    half8 h11 = (u11 + v11) + (tb1a + fh1 * (td1 - tb1a));

    float acc0 = 0.0f, acc1 = 0.0f;
    #pragma unroll
    for (int c = 0; c < 8; ++c) {
        float hf0 = (float)h00[c];
        acc0 += w2c[c] * hf0 * __builtin_amdgcn_rcpf(1.0f + __expf(-hf0));
        float hf1 = (float)h10[c];
        acc1 += w2c[c] * hf1 * __builtin_amdgcn_rcpf(1.0f + __expf(-hf1));
    }
    #pragma unroll
    for (int c = 0; c < 8; ++c) {
        float hf0 = (float)h01[c];
        acc0 += w2c[8 + c] * hf0 * __builtin_amdgcn_rcpf(1.0f + __expf(-hf0));
        float hf1 = (float)h11[c];
        acc1 += w2c[8 + c] * hf1 * __builtin_amdgcn_rcpf(1.0f + __expf(-hf1));
    }
    #pragma unroll
    for (int off = 1; off < 16; off <<= 1) {
        acc0 += __shfl_xor(acc0, off);
        acc1 += __shfl_xor(acc1, off);
    }

    if (l == 0) {
        float2 o;
        o.x = acc0 + b_b2[0];
        o.y = acc1 + b_b2[0];
        *(float2*)&bijV[slot0] = o;
    }
}

// ---------------------------------------------------------------------------
// F2: node-parallel softmax + outer-product. 16 lanes/node, CSR segment kept
// entirely in registers (CAP=64 -> 4 slots/lane, statically indexed).
// ---------------------------------------------------------------------------
__global__ __launch_bounds__(256) void node_reduce_kernel(
    const int* __restrict__ start, const int* __restrict__ cnt,
    const float* __restrict__ bijV, const float4* __restrict__ geom,
    const float* __restrict__ bsumseed, const float* __restrict__ out_ai,
    float* __restrict__ out_sigma, float* __restrict__ out_sg)
{
    const int grp = threadIdx.x >> 4;
    const int l = threadIdx.x & 15;
    const int g = blockIdx.x * 16 + grp;   // 1250*16 = 20000 exact
    const int st = start[g];
    const int deg = min(cnt[g], CAP);

    float bj[4], ex[4], ey[4], ez[4];
    bool ok[4];
    float m = -1e30f;
    #pragma unroll
    for (int k = 0; k < 4; ++k) {
        int i = l + k * 16;
        ok[k] = (i < deg);
        if (ok[k]) {
            float4 o = geom[st + i];
            bj[k] = bijV[st + i];
            ex[k] = o.x; ey[k] = o.y; ez[k] = o.z;
        } else {
            bj[k] = -1e30f; ex[k] = 0.0f; ey[k] = 0.0f; ez[k] = 0.0f;
        }
        m = fmaxf(m, bj[k]);
    }
    #pragma unroll
    for (int off = 1; off < 16; off <<= 1) m = fmaxf(m, __shfl_xor(m, off));

    float g4[4];
    float ssum = 0.0f;
    #pragma unroll
    for (int k = 0; k < 4; ++k) {
        g4[k] = ok[k] ? __expf(bj[k] - m) : 0.0f;
        ssum += g4[k];
    }
    #pragma unroll
    for (int off = 1; off < 16; off <<= 1) ssum += __shfl_xor(ssum, off);

    float invt = 1.0f / (ssum + bsumseed[g]);   // seed = ci + 1e-7

    float a0 = 0, a1 = 0, a2 = 0, a3 = 0, a4 = 0, a5 = 0, a6 = 0;
    #pragma unroll
    for (int k = 0; k < 4; ++k) {
        float gm = g4[k] * invt;
        a0 += gm * ex[k] * ex[k]; a1 += gm * ey[k] * ey[k]; a2 += gm * ez[k] * ez[k];
        a3 += gm * ex[k] * ey[k]; a4 += gm * ex[k] * ez[k]; a5 += gm * ey[k] * ez[k];
        a6 += gm;
    }
    #pragma unroll
    for (int off = 1; off < 16; off <<= 1) {
        a0 += __shfl_xor(a0, off); a1 += __shfl_xor(a1, off);
        a2 += __shfl_xor(a2, off); a3 += __shfl_xor(a3, off);
        a4 += __shfl_xor(a4, off); a5 += __shfl_xor(a5, off);
        a6 += __shfl_xor(a6, off);
    }

    if (l == 0) {
        float ai = out_ai[g];
        float* sg = &out_sigma[g * 9];
        float d0 = ai + 1e-6f;
        sg[0] = d0 - ai * a0;
        sg[1] = -ai * a3;
        sg[2] = -ai * a4;
        sg[3] = -ai * a3;
        sg[4] = d0 - ai * a1;
        sg[5] = -ai * a5;
        sg[6] = -ai * a4;
        sg[7] = -ai * a5;
        sg[8] = d0 - ai * a2;
        out_sg[g] = a6;
    }
}

extern "C" void kernel_launch(void* const* d_in, const int* in_sizes, int n_in,
                              void* d_out, int out_size, void* d_ws, size_t ws_size,
                              hipStream_t stream)
{
    const float* nf    = (const float*)d_in[0];
    const float* pos   = (const float*)d_in[1];
    const int*   ei    = (const int*)  d_in[2];
    const float* W_ai1 = (const float*)d_in[3];
    const float* b_ai1 = (const float*)d_in[4];
    const float* W_ai2 = (const float*)d_in[5];
    const float* b_ai2 = (const float*)d_in[6];
    const float* W_ci1 = (const float*)d_in[7];
    const float* b_ci1 = (const float*)d_in[8];
    const float* W_ci2 = (const float*)d_in[9];
    const float* b_ci2 = (const float*)d_in[10];
    const float* W_sc  = (const float*)d_in[11];
    const float* b_sc  = (const float*)d_in[12];
    const float* W_ed  = (const float*)d_in[13];
    const float* b_ed  = (const float*)d_in[14];
    const float* W_b1  = (const float*)d_in[15];
    const float* b_b1  = (const float*)d_in[16];
    const float* W_b2  = (const float*)d_in[17];
    const float* b_b2  = (const float*)d_in[18];

    // Byte-based bump allocator (256-B aligned).
    char* pb = (char*)d_ws;
    auto alloc = [&](size_t bytes) -> void* {
        void* r = (void*)pb;
        pb += (bytes + 255) & ~(size_t)255;
        return r;
    };
    float*          We      = (float*)         alloc(8192 * 4);
    float*          c0      = (float*)         alloc(256 * 4);
    _Float16*       Tab     = (_Float16*)      alloc((size_t)QTAB * 256 * 2);
    unsigned short* Bpack   = (unsigned short*)alloc((size_t)256 * 1024 * 2);
    unsigned short* scalp   = (unsigned short*)alloc((size_t)N_NODES * 256 * 2);
    _Float16*       u       = (_Float16*)      alloc((size_t)N_NODES * 256 * 2);
    _Float16*       v       = (_Float16*)      alloc((size_t)N_NODES * 256 * 2);
    float*          bsumseed= (float*)         alloc((size_t)N_NODES * 4);
    int*            cnt     = (int*)           alloc((size_t)N_NODES * 4);
    int*            startA  = (int*)           alloc((size_t)N_NODES * 4);
    int*            rank    = (int*)           alloc((size_t)E_EDGES * 4);
    int2*           sd      = (int2*)          alloc((size_t)E_EDGES * 8);
    float4*         geom    = (float4*)        alloc((size_t)E_EDGES * 16);
    float*          bijV    = (float*)         alloc((size_t)E_EDGES * 4);

    float* out       = (float*)d_out;
    float* out_sigma = out;                  // N*9
    float* out_ai    = out + N_NODES * 9;    // N
    float* out_sg    = out + N_NODES * 10;   // N

    prep_kernel<<<240, 256, 0, stream>>>(W_sc, W_ed, W_b1, b_sc, b_ed, b_b1, W_ai1, W_ci1,
                                         Bpack, We, c0, cnt);
    aux_kernel<<<8298, 256, 0, stream>>>(ei, cnt, rank, We, Tab, nf, scalp);
    scan_kernel<<<1, 1024, (size_t)N_NODES * 4, stream>>>(cnt, startA);
    node_mfma_kernel<<<2500, 256, 0, stream>>>(scalp, Bpack, c0, b_ai1, W_ai2, b_ai2,
                                               b_ci1, W_ci2, b_ci2, u, v, bsumseed, out_ai);
    edge_geom_kernel<<<1250, 256, 0, stream>>>(ei, startA, rank, pos, sd, geom);
    edge_bij_kernel<<<10000, 256, 0, stream>>>(sd, geom, u, v, Tab, W_b2, b_b2, bijV);
    node_reduce_kernel<<<1250, 256, 0, stream>>>(startA, cnt, bijV, geom, bsumseed, out_ai,
                                                 out_sigma, out_sg);
}